// Round 12
// baseline (220.775 us; speedup 1.0000x reference)
//
#include <hip/hip_runtime.h>

// Problem constants
#define B_  512
#define T_  256
#define C_  256
#define H_  64
#define BT_ (B_ * T_)   // 131072

typedef unsigned short u16;
typedef unsigned int u32;
typedef __attribute__((ext_vector_type(8))) __bf16 bf16x8;
typedef __attribute__((ext_vector_type(8))) u16 u16x8;
typedef __attribute__((ext_vector_type(2))) u32 u32x2;
typedef __attribute__((ext_vector_type(4))) float f32x4;

__device__ __forceinline__ u16 f2bf(float f) {
  union { float f; unsigned u; } v; v.f = f;
  unsigned r = v.u + 0x7fffu + ((v.u >> 16) & 1u);   // RNE
  return (u16)(r >> 16);
}

__device__ __forceinline__ f32x4 mfma16(bf16x8 a, bf16x8 b, f32x4 c) {
  return __builtin_amdgcn_mfma_f32_16x16x32_bf16(a, b, c, 0, 0, 0);
}

// ---------------------------------------------------------------------------
// Kernel 0: W [C][H] fp32 x3  ->  wt bf16 [3][H][C]  (transposed, K-contig)
// ---------------------------------------------------------------------------
__global__ __launch_bounds__(256) void wconv_kernel(
    const float* __restrict__ Wq, const float* __restrict__ Wk,
    const float* __restrict__ Wv, u16* __restrict__ wt) {
  int idx = blockIdx.x * 256 + threadIdx.x;      // 0 .. 49151
  int w   = idx >> 14;
  int rem = idx & 16383;
  int h   = rem >> 8;
  int c   = rem & 255;
  const float* W = (w == 0) ? Wq : (w == 1) ? Wk : Wv;
  wt[idx] = f2bf(W[c * H_ + h]);
}

// ---------------------------------------------------------------------------
// FUSED kernel v4: one block per batch, 1024 threads (16 waves).
// Evidence r8 vs r10: 2->4 waves/SIMD changed NOTHING -> block-scope
// serialization, prime suspect phase-1's barrier every 32-K step (9/block,
// each draining vmcnt(0) with only ~100cyc of compute to hide ~600cyc HBM).
// v4: K-step 128, single-buffered sB[192][136] (52KB), barriers 9 -> 4.
//   - 48 MFMA per barrier interval; A sub-step prefetch free-runs within
//     the half (no barriers between sub-steps -> cross-wave overlap works).
//   - half-2 B global loads issued at START of half-1 compute (T14),
//     held in regs, ds_written after the drain barrier.
// Phase 2 (v3 swapped-QK^T no-max softmax) UNCHANGED for attribution.
// LDS total: 52224+36864+36864+33792 = 159744 <= 163840.
// ---------------------------------------------------------------------------
__global__ __launch_bounds__(1024, 4) void fused_kernel(
    const float* __restrict__ x, const u16* __restrict__ wt,
    float* __restrict__ out) {
  __shared__ u16 sB[192 * 136];    // B slice [192 rows][128k +8 pad]  52224 B
  __shared__ u16 sQP[256 * 72];    // Q (phase 1/2a), P (phase 2b)    36864 B
  __shared__ u16 sK[256 * 72];     //                                 36864 B
  __shared__ u16 sVt[64 * 264];    // transposed V                    33792 B

  const int tid  = threadIdx.x;
  const int wave = tid >> 6, lane = tid & 63;
  const int lr = lane & 15, lg = lane >> 4;
  const int b = blockIdx.x;

  const float* xb = x + (size_t)b * T_ * C_;
  float* ob = out + (size_t)b * T_ * H_;

  const f32x4 fzero = {0.f, 0.f, 0.f, 0.f};

  // ================= Phase 1: QKV GEMM (v4) =================
  f32x4 acc[12];
#pragma unroll
  for (int nt = 0; nt < 12; ++nt) acc[nt] = fzero;

  const float* xp0 = xb + (size_t)(wave * 16 + lr) * C_ + lg * 8;

  float4 aA[2][2];   // [buf][half-of-8-floats]
  u16x8  breg[4];    // B staging regs: thread stages 4 slots of 16B

  const int brow = tid >> 2, bc0 = (tid & 3) * 8;   // valid for tid<768

  // load B half h (k = h*128..+128) into regs: 768 thr x 4 x 16B = 48KB
#define LOAD_B_HALF(h)                                                      \
  {                                                                         \
    if (tid < 768) {                                                        \
      _Pragma("unroll") for (int i = 0; i < 4; ++i)                         \
        breg[i] = *(const u16x8*)(wt + brow * C_ + (h) * 128 + bc0 + i * 32); \
    }                                                                       \
  }

#define WRITE_B_HALF()                                                      \
  {                                                                         \
    if (tid < 768) {                                                        \
      _Pragma("unroll") for (int i = 0; i < 4; ++i)                         \
        *(u16x8*)&sB[brow * 136 + bc0 + i * 32] = breg[i];                  \
    }                                                                       \
  }

  // kk is the ABSOLUTE k base (0..224, step 32)
#define LOAD_A(buf, kk)                                     \
  {                                                         \
    aA[buf][0] = *(const float4*)(xp0 + (kk));              \
    aA[buf][1] = *(const float4*)(xp0 + (kk) + 4);          \
  }

  // s = sub-step within the half (k-offset in sB = s*32)
#define COMPUTE_SUB(buf, s)                                                  \
  {                                                                          \
    u16x8 au;                                                                \
    au[0] = f2bf(aA[buf][0].x); au[1] = f2bf(aA[buf][0].y);                  \
    au[2] = f2bf(aA[buf][0].z); au[3] = f2bf(aA[buf][0].w);                  \
    au[4] = f2bf(aA[buf][1].x); au[5] = f2bf(aA[buf][1].y);                  \
    au[6] = f2bf(aA[buf][1].z); au[7] = f2bf(aA[buf][1].w);                  \
    bf16x8 af = __builtin_bit_cast(bf16x8, au);                              \
    _Pragma("unroll") for (int nt = 0; nt < 12; ++nt) {                      \
      bf16x8 bf = *(const bf16x8*)&sB[(nt * 16 + lr) * 136 + (s) * 32 + lg * 8]; \
      acc[nt] = mfma16(af, bf, acc[nt]);                                     \
    }                                                                        \
  }

  // ---- prologue ----
  LOAD_B_HALF(0);
  LOAD_A(0, 0);
  WRITE_B_HALF();
  __syncthreads();                       // barrier 1: sB half-0 ready

  // ---- half 0 (k 0..127): sub-steps free-run, no barriers between ----
  LOAD_B_HALF(1);                        // issue half-1 B loads early (T14)
  LOAD_A(1, 32);  COMPUTE_SUB(0, 0);
  LOAD_A(0, 64);  COMPUTE_SUB(1, 1);
  LOAD_A(1, 96);  COMPUTE_SUB(0, 2);
  LOAD_A(0, 128); COMPUTE_SUB(1, 3);     // also prefetch half-1 sub-0 A
  __syncthreads();                       // barrier 2: all done READING half-0
  WRITE_B_HALF();                        // overwrite sB with half-1
  __syncthreads();                       // barrier 3: sB half-1 ready

  // ---- half 1 (k 128..255) ----
  LOAD_A(1, 160); COMPUTE_SUB(0, 0);
  LOAD_A(0, 192); COMPUTE_SUB(1, 1);
  LOAD_A(1, 224); COMPUTE_SUB(0, 2);
  COMPUTE_SUB(1, 3);

  // Epilogue: acc (C-layout: row=lg*4+i, col=lr in 16-tile) -> LDS.
  {
    const int rb0 = wave * 16 + lg * 4;
#pragma unroll
    for (int nt = 0; nt < 12; ++nt) {
      const int wsel = nt >> 2;
      const int h = (nt & 3) * 16 + lr;
#pragma unroll
      for (int i = 0; i < 4; ++i) {
        const int r = rb0 + i;
        u16 val = f2bf(acc[nt][i]);
        if (wsel == 0)      sQP[r * 72 + h] = val;
        else if (wsel == 1) sK[r * 72 + h] = val;
        else                sVt[h * 264 + r] = val;  // transpose (once)
      }
    }
  }
  __syncthreads();                       // barrier 4: phase transition

  // ================= Phase 2: causal attention (v3, unchanged) ============
  const int c  = wave;        // 16-row chunk, 0..15
  const int r0 = c * 16;
  const int tl = c >> 2;      // diagonal KV-tile index

  // Q into regs BEFORE sP overlays sQ (same-wave region; fence below).
  bf16x8 qf[2];
#pragma unroll
  for (int ks = 0; ks < 2; ++ks)
    qf[ks] = *(const bf16x8*)&sQP[(r0 + lr) * 72 + ks * 32 + lg * 8];
  __builtin_amdgcn_wave_barrier();   // qf reads before P writes

  u16* sPw = sQP + wave * (16 * 72);   // per-wave P buffer [16 q-rows][72]

  f32x4 o[4];
#pragma unroll
  for (int ht = 0; ht < 4; ++ht) o[ht] = fzero;
  float lrow = 0.f;                  // denominator for q-row = lr
  const int qrow = r0 + lr;

  for (int t = 0; t <= tl; ++t) {
    // ---- S^T = K Q^T: lane owns (key = t*64+nt*16+lg*4+i, q = lr) ----
    f32x4 st[4];
#pragma unroll
    for (int nt = 0; nt < 4; ++nt) st[nt] = fzero;
#pragma unroll
    for (int ks = 0; ks < 2; ++ks) {
#pragma unroll
      for (int nt = 0; nt < 4; ++nt) {
        bf16x8 kf = *(const bf16x8*)&sK[(t * 64 + nt * 16 + lr) * 72 + ks * 32 + lg * 8];
        st[nt] = mfma16(kf, qf[ks], st[nt]);
      }
    }

    // ---- no-max softmax numerator + vectorized P store ----
    float rs = 0.f;
#pragma unroll
    for (int nt = 0; nt < 4; ++nt) {
      float p[4];
#pragma unroll
      for (int i = 0; i < 4; ++i) {
        const int key = t * 64 + nt * 16 + lg * 4 + i;
        float e = __expf(st[nt][i] * 0.0625f);   // |arg| <~ 3: safe
        p[i] = (key > qrow) ? 0.f : e;           // causal mask
        rs += p[i];
      }
      u32 lo = (u32)f2bf(p[0]) | ((u32)f2bf(p[1]) << 16);
      u32 hi = (u32)f2bf(p[2]) | ((u32)f2bf(p[3]) << 16);
      u32x2 pv2 = {lo, hi};
      *(u32x2*)&sPw[lr * 72 + nt * 16 + lg * 4] = pv2;  // b64, ~2-way banks
    }
    rs += __shfl_xor(rs, 16);   // combine across the 4 lanes sharing lr
    rs += __shfl_xor(rs, 32);
    lrow += rs;

    __builtin_amdgcn_wave_barrier();   // P writes before P reads

    // ---- O += P V ----
#pragma unroll
    for (int ks2 = 0; ks2 < 2; ++ks2) {
      bf16x8 pf = *(const bf16x8*)&sPw[lr * 72 + ks2 * 32 + lg * 8];
#pragma unroll
      for (int ht = 0; ht < 4; ++ht) {
        bf16x8 vf = *(const bf16x8*)&sVt[(ht * 16 + lr) * 264 + t * 64 + ks2 * 32 + lg * 8];
        o[ht] = mfma16(pf, vf, o[ht]);
      }
    }
    __builtin_amdgcn_wave_barrier();   // next tile's P writes after reads
  }

  // ---- epilogue: fetch denominators (q = lg*4+i lives at lane lr=q) ----
#pragma unroll
  for (int i = 0; i < 4; ++i) {
    const float lq = __shfl(lrow, (lane & 48) + lg * 4 + i);
    const float inv = 1.f / lq;
    const int r = r0 + lg * 4 + i;
#pragma unroll
    for (int ht = 0; ht < 4; ++ht)
      ob[r * H_ + ht * 16 + lr] = o[ht][i] * inv;
  }
#undef LOAD_B_HALF
#undef WRITE_B_HALF
#undef LOAD_A
#undef COMPUTE_SUB
}

// ---------------------------------------------------------------------------
extern "C" void kernel_launch(void* const* d_in, const int* in_sizes, int n_in,
                              void* d_out, int out_size, void* d_ws, size_t ws_size,
                              hipStream_t stream) {
  const float* x  = (const float*)d_in[0];
  const float* Wq = (const float*)d_in[1];
  const float* Wk = (const float*)d_in[2];
  const float* Wv = (const float*)d_in[3];
  float* out = (float*)d_out;

  u16* wt = (u16*)d_ws;   // 3*64*256 bf16 = 96 KiB

  wconv_kernel<<<192, 256, 0, stream>>>(Wq, Wk, Wv, wt);
  fused_kernel<<<B_, 1024, 0, stream>>>(x, wt, out);
}